// Round 9
// baseline (1577.903 us; speedup 1.0000x reference)
//
#include <hip/hip_runtime.h>
#include <math.h>

// Force numpy-style arithmetic: no FMA contraction, no reassociation.
// RF kernels use explicit fmaf() where fusion is wanted (smooth ops).
#pragma clang fp contract(off)
#pragma clang fp reassociate(off)

#define NU 100000
#define NI 50000
#define NT 150000
#define DD 64
#define NE 2000000
#define NTD (NT * DD)
#define NPART 8
#define PARTW (NT / NPART)     // 18750 nodes per XCD partition
#define NCHUNK 256
#define CHW ((NE + NCHUNK - 1) / NCHUNK)   // 7813 edges per chunk

__global__ __launch_bounds__(256) void zero_k(int* __restrict__ p, int n) {
  int i = blockIdx.x * 256 + threadIdx.x;
  if (i < n) p[i] = 0;
}

// XCD-partitioned count with non-temporal edge reads (stream, evict-first) so the
// cnt lines stay resident in the owning XCD's L2.
__global__ __launch_bounds__(256) void count_k(const int* __restrict__ eu, const int* __restrict__ ei,
                                               int* __restrict__ cnt) {
  int part = blockIdx.x & 7;
  int chunk = blockIdx.x >> 3;
  int lo = part * PARTW, hi = lo + PARTW;
  int e0 = chunk * CHW;
  int e1 = e0 + CHW; if (e1 > NE) e1 = NE;
  for (int e = e0 + threadIdx.x; e < e1; e += 256) {
    int u = __builtin_nontemporal_load(&eu[e]);
    int it = NU + __builtin_nontemporal_load(&ei[e]);
    if (u >= lo && u < hi) atomicAdd(&cnt[u], 1);
    if (it >= lo && it < hi) atomicAdd(&cnt[it], 1);
  }
}

__global__ __launch_bounds__(1024) void scanA_k(const int* __restrict__ cnt, int* __restrict__ lexcl,
                                                int* __restrict__ partials, int n) {
  int idx = blockIdx.x * 1024 + threadIdx.x;
  int v = (idx < n) ? cnt[idx] : 0;
  int lane = threadIdx.x & 63;
  int wid = threadIdx.x >> 6;
  int x = v;
#pragma unroll
  for (int off = 1; off < 64; off <<= 1) {
    int y = __shfl_up(x, off, 64);
    if (lane >= off) x += y;
  }
  __shared__ int wtot[16], woff[16];
  if (lane == 63) wtot[wid] = x;
  __syncthreads();
  if (threadIdx.x == 0) {
    int a = 0;
#pragma unroll
    for (int w = 0; w < 16; ++w) { woff[w] = a; a += wtot[w]; }
    partials[blockIdx.x] = a;
  }
  __syncthreads();
  if (idx < n) lexcl[idx] = x - v + woff[wid];
}

__global__ __launch_bounds__(64) void scanB_k(int* __restrict__ partials, int* __restrict__ row, int nchunks) {
  int lane = threadIdx.x;
  int carry = 0;
  for (int base = 0; base < nchunks; base += 64) {
    int idx = base + lane;
    int v = (idx < nchunks) ? partials[idx] : 0;
    int x = v;
#pragma unroll
    for (int off = 1; off < 64; off <<= 1) {
      int y = __shfl_up(x, off, 64);
      if (lane >= off) x += y;
    }
    if (idx < nchunks) partials[idx] = carry + x - v;
    carry += __shfl(x, 63, 64);
  }
  if (lane == 0) row[NT] = carry;
}

__global__ __launch_bounds__(1024) void scanC_k(int* __restrict__ row, int* __restrict__ cursor,
                                                float* __restrict__ coef, const int* __restrict__ partials, int n) {
  int idx = blockIdx.x * 1024 + threadIdx.x;
  if (idx >= n) return;
  int c = cursor[idx];  // raw count
  int fin = row[idx] + partials[blockIdx.x];
  row[idx] = fin;
  cursor[idx] = fin;
  coef[idx] = (float)pow((double)(c > 0 ? c : 1), -0.5);
}

// XCD-partitioned fill with non-temporal edge reads: the streaming eu/ei traffic no
// longer evicts the partition's dirty eid/cursor lines (2 MB slice < 4 MB L2), so
// scatter lines get fully populated before writeback.
__global__ __launch_bounds__(256) void fill_k(const int* __restrict__ eu, const int* __restrict__ ei,
                                              int* __restrict__ cursor, int* __restrict__ eid) {
  int part = blockIdx.x & 7;
  int chunk = blockIdx.x >> 3;
  int lo = part * PARTW, hi = lo + PARTW;
  int e0 = chunk * CHW;
  int e1 = e0 + CHW; if (e1 > NE) e1 = NE;
  for (int e = e0 + threadIdx.x; e < e1; e += 256) {
    int u = __builtin_nontemporal_load(&eu[e]);
    int it = NU + __builtin_nontemporal_load(&ei[e]);
    if (u >= lo && u < hi) {
      int p = atomicAdd(&cursor[u], 1);
      eid[p] = e;
    }
    if (it >= lo && it < hi) {
      int p = atomicAdd(&cursor[it], 1);
      eid[p] = e;
    }
  }
}

// Rank-sort each segment by edge id -> col/seid in exact edge order (deterministic).
__global__ __launch_bounds__(256) void sort_k(const int* __restrict__ row, const int* __restrict__ eid,
                                              const int* __restrict__ eu, const int* __restrict__ ei,
                                              int* __restrict__ col, int* __restrict__ seid) {
  int wv = (blockIdx.x * blockDim.x + threadIdx.x) >> 6;
  int lane = threadIdx.x & 63;
  if (wv >= NT) return;
  int beg = row[wv], end = row[wv + 1];
  for (int idx = beg + lane; idx < end; idx += 64) {
    int my = eid[idx];
    int r = 0;
    for (int j = beg; j < end; ++j) r += (eid[j] < my);
    col[beg + r] = (wv < NU) ? (NU + ei[my]) : eu[my];
    seid[beg + r] = my;
  }
}

__global__ __launch_bounds__(256) void init_k(const float* __restrict__ ue, const float* __restrict__ ie,
                                              float* __restrict__ emb, float* __restrict__ acc) {
  int idx = blockIdx.x * blockDim.x + threadIdx.x;
  int stride = gridDim.x * blockDim.x;
  for (int j = idx; j < NTD; j += stride) {
    float v = (j < NU * DD) ? ue[j] : ie[j - NU * DD];
    emb[j] = v;
    acc[j] = v;
  }
}

// GCN layer: 4 nodes/wave, 16 lanes x float4 dims, depth-4+4 chunked gather pipeline.
// Arithmetic bit-identical: per-dim strict edge-order sum, separate mul/add rounding;
// noise pairwise-sum + fixed tree. LAST=1 fuses the layer mean.
template <int LAST>
__global__ __launch_bounds__(256) void gcn4_k(const float* __restrict__ in, float* __restrict__ out,
                                              float* __restrict__ acc,
                                              const int* __restrict__ row, const int* __restrict__ col,
                                              const float* __restrict__ coef, const float* __restrict__ nz_l) {
  int wave = (blockIdx.x * blockDim.x + threadIdx.x) >> 6;
  int lane = threadIdx.x & 63;
  int g = lane >> 4, q = lane & 15;
  int node = wave * 4 + g;
  if (node >= NT) return;
  int beg = row[node], end = row[node + 1];
  float cn = coef[node];
  float sx = 0.f, sy = 0.f, sz = 0.f, sw = 0.f;

#define GLD(dv, dc, kk) { int m_ = col[kk]; dc = coef[m_]; dv = *(const float4*)(in + (size_t)m_ * DD + q * 4); }
  float4 cv0, cv1, cv2, cv3;
  float cc0, cc1, cc2, cc3;
  int rem = end - beg;
  int k4end = end - (rem & 3);
  int k = beg;
  if (k < k4end) {
    GLD(cv0, cc0, k) GLD(cv1, cc1, k + 1) GLD(cv2, cc2, k + 2) GLD(cv3, cc3, k + 3)
  }
  for (; k < k4end; k += 4) {
    float4 nv0, nv1, nv2, nv3;
    float nc0, nc1, nc2, nc3;
    bool more = (k + 4) < k4end;
    if (more) {
      GLD(nv0, nc0, k + 4) GLD(nv1, nc1, k + 5) GLD(nv2, nc2, k + 6) GLD(nv3, nc3, k + 7)
    }
    {
      float w = cn * cc0;
      sx = sx + (cv0.x * w); sy = sy + (cv0.y * w); sz = sz + (cv0.z * w); sw = sw + (cv0.w * w);
    }
    {
      float w = cn * cc1;
      sx = sx + (cv1.x * w); sy = sy + (cv1.y * w); sz = sz + (cv1.z * w); sw = sw + (cv1.w * w);
    }
    {
      float w = cn * cc2;
      sx = sx + (cv2.x * w); sy = sy + (cv2.y * w); sz = sz + (cv2.z * w); sw = sw + (cv2.w * w);
    }
    {
      float w = cn * cc3;
      sx = sx + (cv3.x * w); sy = sy + (cv3.y * w); sz = sz + (cv3.z * w); sw = sw + (cv3.w * w);
    }
    if (more) {
      cv0 = nv0; cc0 = nc0; cv1 = nv1; cc1 = nc1;
      cv2 = nv2; cc2 = nc2; cv3 = nv3; cc3 = nc3;
    }
  }
  for (; k < end; ++k) {  // tail <= 3
    float4 v; float c;
    GLD(v, c, k)
    float w = cn * c;
    sx = sx + (v.x * w); sy = sy + (v.y * w); sz = sz + (v.z * w); sw = sw + (v.w * w);
  }
#undef GLD

  // Noise norm, bit-identical: r[j] = sum over k of sq[8k+j] (sequential), tree combine.
  float4 nzv = *(const float4*)(nz_l + (size_t)node * DD + q * 4);
  float4 sq;
  sq.x = nzv.x * nzv.x; sq.y = nzv.y * nzv.y;
  sq.z = nzv.z * nzv.z; sq.w = nzv.w * nzv.w;
  float rA0 = 0.f, rA1 = 0.f, rA2 = 0.f, rA3 = 0.f;
  float rB0 = 0.f, rB1 = 0.f, rB2 = 0.f, rB3 = 0.f;
  int base = g * 16;
#pragma unroll
  for (int kk = 0; kk < 8; ++kk) {
    int le = base + 2 * kk, lo = le + 1;
    rA0 = rA0 + __shfl(sq.x, le, 64);
    rA1 = rA1 + __shfl(sq.y, le, 64);
    rA2 = rA2 + __shfl(sq.z, le, 64);
    rA3 = rA3 + __shfl(sq.w, le, 64);
    rB0 = rB0 + __shfl(sq.x, lo, 64);
    rB1 = rB1 + __shfl(sq.y, lo, 64);
    rB2 = rB2 + __shfl(sq.z, lo, 64);
    rB3 = rB3 + __shfl(sq.w, lo, 64);
  }
  float t01 = rA0 + rA1, t23 = rA2 + rA3;
  float t45 = rB0 + rB1, t67 = rB2 + rB3;
  float tot = (t01 + t23) + (t45 + t67);
  float nrm = __fsqrt_rn(tot);
  float den = fmaxf(nrm, 1e-12f);
  float4 o;
  {
    float nn = nzv.x / den;
    float sg = (sx > 0.f) ? 1.f : ((sx < 0.f) ? -1.f : 0.f);
    o.x = sx + ((sg * nn) * 0.2f);
  }
  {
    float nn = nzv.y / den;
    float sg = (sy > 0.f) ? 1.f : ((sy < 0.f) ? -1.f : 0.f);
    o.y = sy + ((sg * nn) * 0.2f);
  }
  {
    float nn = nzv.z / den;
    float sg = (sz > 0.f) ? 1.f : ((sz < 0.f) ? -1.f : 0.f);
    o.z = sz + ((sg * nn) * 0.2f);
  }
  {
    float nn = nzv.w / den;
    float sg = (sw > 0.f) ? 1.f : ((sw < 0.f) ? -1.f : 0.f);
    o.w = sw + ((sg * nn) * 0.2f);
  }
  size_t boff = (size_t)node * DD + q * 4;
  float4 a = *(const float4*)(acc + boff);
  if (LAST) {
    float4 mo;
    mo.x = (a.x + o.x) * 0.25f;
    mo.y = (a.y + o.y) * 0.25f;
    mo.z = (a.z + o.z) * 0.25f;
    mo.w = (a.w + o.w) * 0.25f;
    *(float4*)(out + boff) = mo;
  } else {
    *(float4*)(out + boff) = o;
    a.x = a.x + o.x; a.y = a.y + o.y; a.z = a.z + o.z; a.w = a.w + o.w;
    *(float4*)(acc + boff) = a;
  }
}

// RF phase 1: expS[e] = exp(dot(emb_u, emb_i)) once per edge. Max-free softmax is exact
// in real arithmetic (rec invariant to max subtraction) and |s| is O(5) -> no overflow.
__global__ __launch_bounds__(256) void score_k(const float* __restrict__ emb,
                                               const int* __restrict__ eu, const int* __restrict__ ei,
                                               float* __restrict__ expS) {
  int wave = (blockIdx.x * blockDim.x + threadIdx.x) >> 6;
  int lane = threadIdx.x & 63;
  int g = lane >> 4, q = lane & 15;
  int e = wave * 4 + g;
  if (e >= NE) return;
  int u = eu[e];
  int it = NU + ei[e];
  float4 a = *(const float4*)(emb + (size_t)u * DD + q * 4);
  float4 b = *(const float4*)(emb + (size_t)it * DD + q * 4);
  float d = fmaf(a.x, b.x, fmaf(a.y, b.y, fmaf(a.z, b.z, a.w * b.w)));
#pragma unroll
  for (int off = 1; off < 16; off <<= 1) d += __shfl_xor(d, off, 64);
  if (q == 0) expS[e] = __expf(d);
}

// RF phase 2 (single pass, no max): per node gather expS via seid, write slot-ordered P,
// Zinv = 1/max(sum, 1e-9).
__global__ __launch_bounds__(256) void zsum_k(const float* __restrict__ expS,
                                              const int* __restrict__ row, const int* __restrict__ seid,
                                              float* __restrict__ P, float* __restrict__ Zinv) {
  int wv = (blockIdx.x * blockDim.x + threadIdx.x) >> 6;
  int lane = threadIdx.x & 63;
  if (wv >= NT) return;
  int beg = row[wv], end = row[wv + 1];
  float zp = 0.f;
  for (int idx = beg + lane; idx < end; idx += 64) {
    float p = expS[seid[idx]];
    P[idx] = p;
    zp += p;
  }
#pragma unroll
  for (int off = 1; off < 64; off <<= 1) zp += __shfl_xor(zp, off, 64);
  if (lane == 0) Zinv[wv] = 1.f / fmaxf(zp, 1e-9f);
}

// RF phase 3: rec = Zinv * sum p*v; out = 0.5*e + 0.5*rec. 4 nodes/wave, depth-4+4 pipeline.
__global__ __launch_bounds__(256) void accum_k(const float* __restrict__ in, float* __restrict__ out,
                                               const int* __restrict__ row, const int* __restrict__ col,
                                               const float* __restrict__ P, const float* __restrict__ Zinv) {
  int wave = (blockIdx.x * blockDim.x + threadIdx.x) >> 6;
  int lane = threadIdx.x & 63;
  int g = lane >> 4, q = lane & 15;
  int node = wave * 4 + g;
  if (node >= NT) return;
  int beg = row[node], end = row[node + 1];
  float rx = 0.f, ry = 0.f, rz = 0.f, rw = 0.f;

#define PLD(dv, dp, kk) { dp = P[kk]; dv = *(const float4*)(in + (size_t)col[kk] * DD + q * 4); }
  float4 cv0, cv1, cv2, cv3;
  float cp0, cp1, cp2, cp3;
  int rem = end - beg;
  int k4end = end - (rem & 3);
  int k = beg;
  if (k < k4end) {
    PLD(cv0, cp0, k) PLD(cv1, cp1, k + 1) PLD(cv2, cp2, k + 2) PLD(cv3, cp3, k + 3)
  }
  for (; k < k4end; k += 4) {
    float4 nv0, nv1, nv2, nv3;
    float np0, np1, np2, np3;
    bool more = (k + 4) < k4end;
    if (more) {
      PLD(nv0, np0, k + 4) PLD(nv1, np1, k + 5) PLD(nv2, np2, k + 6) PLD(nv3, np3, k + 7)
    }
    rx = fmaf(cp0, cv0.x, rx); ry = fmaf(cp0, cv0.y, ry); rz = fmaf(cp0, cv0.z, rz); rw = fmaf(cp0, cv0.w, rw);
    rx = fmaf(cp1, cv1.x, rx); ry = fmaf(cp1, cv1.y, ry); rz = fmaf(cp1, cv1.z, rz); rw = fmaf(cp1, cv1.w, rw);
    rx = fmaf(cp2, cv2.x, rx); ry = fmaf(cp2, cv2.y, ry); rz = fmaf(cp2, cv2.z, rz); rw = fmaf(cp2, cv2.w, rw);
    rx = fmaf(cp3, cv3.x, rx); ry = fmaf(cp3, cv3.y, ry); rz = fmaf(cp3, cv3.z, rz); rw = fmaf(cp3, cv3.w, rw);
    if (more) {
      cv0 = nv0; cp0 = np0; cv1 = nv1; cp1 = np1;
      cv2 = nv2; cp2 = np2; cv3 = nv3; cp3 = np3;
    }
  }
  for (; k < end; ++k) {
    float4 v; float p;
    PLD(v, p, k)
    rx = fmaf(p, v.x, rx); ry = fmaf(p, v.y, ry); rz = fmaf(p, v.z, rz); rw = fmaf(p, v.w, rw);
  }
#undef PLD

  float zi = Zinv[node];
  size_t boff = (size_t)node * DD + q * 4;
  float4 e = *(const float4*)(in + boff);
  float4 o;
  o.x = 0.5f * e.x + 0.5f * (rx * zi);
  o.y = 0.5f * e.y + 0.5f * (ry * zi);
  o.z = 0.5f * e.z + 0.5f * (rz * zi);
  o.w = 0.5f * e.w + 0.5f * (rw * zi);
  *(float4*)(out + boff) = o;
}

extern "C" void kernel_launch(void* const* d_in, const int* in_sizes, int n_in,
                              void* d_out, int out_size, void* d_ws, size_t ws_size,
                              hipStream_t stream) {
  const float* user_emb = (const float*)d_in[0];
  const float* item_emb = (const float*)d_in[1];
  const float* noise    = (const float*)d_in[2];
  const int*   edge_u   = (const int*)d_in[3];
  const int*   edge_i   = (const int*)d_in[4];
  float* out = (float*)d_out;

  // ws layout (~136 MB)
  float* embA = (float*)d_ws;                      // NTD
  float* embB = embA + (size_t)NTD;                // NTD
  float* coef = embB + (size_t)NTD;                // NT+16
  int*   row  = (int*)(coef + (NT + 16));          // NT+16
  int*   cursor = row + (NT + 16);                 // NT+16
  int*   partials = cursor + (NT + 16);            // 256
  int*   eidt = partials + 256;                    // 2E (dead after sort_k -> reused as P)
  int*   col  = eidt + 2 * (size_t)NE;             // 2E
  int*   seid = col + 2 * (size_t)NE;              // 2E
  float* S    = (float*)(seid + 2 * (size_t)NE);   // E  (expS)
  float* Zinv = S + NE;                            // NT+16
  float* P    = (float*)eidt;                      // 2E (aliases eidt)

  float* acc = out;  // layer-mean accumulator lives in d_out until the final RF pass

  const int nchunks = (NT + 1023) / 1024;

  zero_k<<<(NT + 255) / 256, 256, 0, stream>>>(cursor, NT);
  count_k<<<NCHUNK * NPART, 256, 0, stream>>>(edge_u, edge_i, cursor);
  scanA_k<<<nchunks, 1024, 0, stream>>>(cursor, row, partials, NT);
  scanB_k<<<1, 64, 0, stream>>>(partials, row, nchunks);
  scanC_k<<<nchunks, 1024, 0, stream>>>(row, cursor, coef, partials, NT);
  fill_k<<<NCHUNK * NPART, 256, 0, stream>>>(edge_u, edge_i, cursor, eidt);

  const int gwave = (NT * 64 + 255) / 256;   // 64-lane-per-node grids (sort, zsum)
  const int g4    = (NT / 4 * 64) / 256;     // 4-node-per-wave grids (gcn4, accum) = 9375
  const int gsc   = (NE / 4 * 64) / 256;     // score grid = 125000

  sort_k<<<gwave, 256, 0, stream>>>(row, eidt, edge_u, edge_i, col, seid);
  init_k<<<4096, 256, 0, stream>>>(user_emb, item_emb, embA, acc);

  // L0: embA -> embB ; L1: embB -> embA ; L2(last, fused mean): embA -> embB
  gcn4_k<0><<<g4, 256, 0, stream>>>(embA, embB, acc, row, col, coef, noise + 0 * (size_t)NTD);
  gcn4_k<0><<<g4, 256, 0, stream>>>(embB, embA, acc, row, col, coef, noise + 1 * (size_t)NTD);
  gcn4_k<1><<<g4, 256, 0, stream>>>(embA, embB, acc, row, col, coef, noise + 2 * (size_t)NTD);

  // RF layer 1: embB -> embA
  score_k<<<gsc, 256, 0, stream>>>(embB, edge_u, edge_i, S);
  zsum_k<<<gwave, 256, 0, stream>>>(S, row, seid, P, Zinv);
  accum_k<<<g4, 256, 0, stream>>>(embB, embA, row, col, P, Zinv);
  // RF layer 2: embA -> out
  score_k<<<gsc, 256, 0, stream>>>(embA, edge_u, edge_i, S);
  zsum_k<<<gwave, 256, 0, stream>>>(S, row, seid, P, Zinv);
  accum_k<<<g4, 256, 0, stream>>>(embA, out, row, col, P, Zinv);
}

// Round 10
// 1194.529 us; speedup vs baseline: 1.3209x; 1.3209x over previous
//
#include <hip/hip_runtime.h>
#include <math.h>

// Force numpy-style arithmetic: no FMA contraction, no reassociation.
// RF kernels use explicit fmaf() where fusion is wanted (smooth ops).
#pragma clang fp contract(off)
#pragma clang fp reassociate(off)

#define NU 100000
#define NI 50000
#define NT 150000
#define DD 64
#define NE 2000000
#define NTD (NT * DD)
#define NPART 8
#define PARTW (NT / NPART)     // 18750 nodes per XCD partition
#define NCHUNK 256
#define CHW ((NE + NCHUNK - 1) / NCHUNK)   // 7813 edges per chunk

__global__ __launch_bounds__(256) void zero_k(int* __restrict__ p, int n) {
  int i = blockIdx.x * 256 + threadIdx.x;
  if (i < n) p[i] = 0;
}

// XCD-partitioned count (r8 form — plain loads; nt-loads measured as a regression).
__global__ __launch_bounds__(256) void count_k(const int* __restrict__ eu, const int* __restrict__ ei,
                                               int* __restrict__ cnt) {
  int part = blockIdx.x & 7;
  int chunk = blockIdx.x >> 3;
  int lo = part * PARTW, hi = lo + PARTW;
  int e0 = chunk * CHW;
  int e1 = e0 + CHW; if (e1 > NE) e1 = NE;
  for (int e = e0 + threadIdx.x; e < e1; e += 256) {
    int u = eu[e];
    int it = NU + ei[e];
    if (u >= lo && u < hi) atomicAdd(&cnt[u], 1);
    if (it >= lo && it < hi) atomicAdd(&cnt[it], 1);
  }
}

__global__ __launch_bounds__(1024) void scanA_k(const int* __restrict__ cnt, int* __restrict__ lexcl,
                                                int* __restrict__ partials, int n) {
  int idx = blockIdx.x * 1024 + threadIdx.x;
  int v = (idx < n) ? cnt[idx] : 0;
  int lane = threadIdx.x & 63;
  int wid = threadIdx.x >> 6;
  int x = v;
#pragma unroll
  for (int off = 1; off < 64; off <<= 1) {
    int y = __shfl_up(x, off, 64);
    if (lane >= off) x += y;
  }
  __shared__ int wtot[16], woff[16];
  if (lane == 63) wtot[wid] = x;
  __syncthreads();
  if (threadIdx.x == 0) {
    int a = 0;
#pragma unroll
    for (int w = 0; w < 16; ++w) { woff[w] = a; a += wtot[w]; }
    partials[blockIdx.x] = a;
  }
  __syncthreads();
  if (idx < n) lexcl[idx] = x - v + woff[wid];
}

__global__ __launch_bounds__(64) void scanB_k(int* __restrict__ partials, int* __restrict__ row, int nchunks) {
  int lane = threadIdx.x;
  int carry = 0;
  for (int base = 0; base < nchunks; base += 64) {
    int idx = base + lane;
    int v = (idx < nchunks) ? partials[idx] : 0;
    int x = v;
#pragma unroll
    for (int off = 1; off < 64; off <<= 1) {
      int y = __shfl_up(x, off, 64);
      if (lane >= off) x += y;
    }
    if (idx < nchunks) partials[idx] = carry + x - v;
    carry += __shfl(x, 63, 64);
  }
  if (lane == 0) row[NT] = carry;
}

__global__ __launch_bounds__(1024) void scanC_k(int* __restrict__ row, int* __restrict__ cursor,
                                                float* __restrict__ coef, const int* __restrict__ partials, int n) {
  int idx = blockIdx.x * 1024 + threadIdx.x;
  if (idx >= n) return;
  int c = cursor[idx];  // raw count
  int fin = row[idx] + partials[blockIdx.x];
  row[idx] = fin;
  cursor[idx] = fin;
  coef[idx] = (float)pow((double)(c > 0 ? c : 1), -0.5);
}

// XCD-partitioned fill (r8 form — plain loads).
__global__ __launch_bounds__(256) void fill_k(const int* __restrict__ eu, const int* __restrict__ ei,
                                              int* __restrict__ cursor, int* __restrict__ eid) {
  int part = blockIdx.x & 7;
  int chunk = blockIdx.x >> 3;
  int lo = part * PARTW, hi = lo + PARTW;
  int e0 = chunk * CHW;
  int e1 = e0 + CHW; if (e1 > NE) e1 = NE;
  for (int e = e0 + threadIdx.x; e < e1; e += 256) {
    int u = eu[e];
    int it = NU + ei[e];
    if (u >= lo && u < hi) {
      int p = atomicAdd(&cursor[u], 1);
      eid[p] = e;
    }
    if (it >= lo && it < hi) {
      int p = atomicAdd(&cursor[it], 1);
      eid[p] = e;
    }
  }
}

// Rank-sort each segment by edge id -> col in exact edge order (deterministic).
// seid no longer needed (zsum_k eliminated by the fused RF pass).
__global__ __launch_bounds__(256) void sort_k(const int* __restrict__ row, const int* __restrict__ eid,
                                              const int* __restrict__ eu, const int* __restrict__ ei,
                                              int* __restrict__ col) {
  int wv = (blockIdx.x * blockDim.x + threadIdx.x) >> 6;
  int lane = threadIdx.x & 63;
  if (wv >= NT) return;
  int beg = row[wv], end = row[wv + 1];
  for (int idx = beg + lane; idx < end; idx += 64) {
    int my = eid[idx];
    int r = 0;
    for (int j = beg; j < end; ++j) r += (eid[j] < my);
    col[beg + r] = (wv < NU) ? (NU + ei[my]) : eu[my];
  }
}

__global__ __launch_bounds__(256) void init_k(const float* __restrict__ ue, const float* __restrict__ ie,
                                              float* __restrict__ emb, float* __restrict__ acc) {
  int idx = blockIdx.x * blockDim.x + threadIdx.x;
  int stride = gridDim.x * blockDim.x;
  for (int j = idx; j < NTD; j += stride) {
    float v = (j < NU * DD) ? ue[j] : ie[j - NU * DD];
    emb[j] = v;
    acc[j] = v;
  }
}

// GCN layer: 4 nodes/wave, 16 lanes x float4 dims, depth-4+4 chunked gather pipeline.
// Arithmetic bit-identical: per-dim strict edge-order sum, separate mul/add rounding;
// noise pairwise-sum + fixed tree. LAST=1 fuses the layer mean.
template <int LAST>
__global__ __launch_bounds__(256) void gcn4_k(const float* __restrict__ in, float* __restrict__ out,
                                              float* __restrict__ acc,
                                              const int* __restrict__ row, const int* __restrict__ col,
                                              const float* __restrict__ coef, const float* __restrict__ nz_l) {
  int wave = (blockIdx.x * blockDim.x + threadIdx.x) >> 6;
  int lane = threadIdx.x & 63;
  int g = lane >> 4, q = lane & 15;
  int node = wave * 4 + g;
  if (node >= NT) return;
  int beg = row[node], end = row[node + 1];
  float cn = coef[node];
  float sx = 0.f, sy = 0.f, sz = 0.f, sw = 0.f;

#define GLD(dv, dc, kk) { int m_ = col[kk]; dc = coef[m_]; dv = *(const float4*)(in + (size_t)m_ * DD + q * 4); }
  float4 cv0, cv1, cv2, cv3;
  float cc0, cc1, cc2, cc3;
  int rem = end - beg;
  int k4end = end - (rem & 3);
  int k = beg;
  if (k < k4end) {
    GLD(cv0, cc0, k) GLD(cv1, cc1, k + 1) GLD(cv2, cc2, k + 2) GLD(cv3, cc3, k + 3)
  }
  for (; k < k4end; k += 4) {
    float4 nv0, nv1, nv2, nv3;
    float nc0, nc1, nc2, nc3;
    bool more = (k + 4) < k4end;
    if (more) {
      GLD(nv0, nc0, k + 4) GLD(nv1, nc1, k + 5) GLD(nv2, nc2, k + 6) GLD(nv3, nc3, k + 7)
    }
    {
      float w = cn * cc0;
      sx = sx + (cv0.x * w); sy = sy + (cv0.y * w); sz = sz + (cv0.z * w); sw = sw + (cv0.w * w);
    }
    {
      float w = cn * cc1;
      sx = sx + (cv1.x * w); sy = sy + (cv1.y * w); sz = sz + (cv1.z * w); sw = sw + (cv1.w * w);
    }
    {
      float w = cn * cc2;
      sx = sx + (cv2.x * w); sy = sy + (cv2.y * w); sz = sz + (cv2.z * w); sw = sw + (cv2.w * w);
    }
    {
      float w = cn * cc3;
      sx = sx + (cv3.x * w); sy = sy + (cv3.y * w); sz = sz + (cv3.z * w); sw = sw + (cv3.w * w);
    }
    if (more) {
      cv0 = nv0; cc0 = nc0; cv1 = nv1; cc1 = nc1;
      cv2 = nv2; cc2 = nc2; cv3 = nv3; cc3 = nc3;
    }
  }
  for (; k < end; ++k) {  // tail <= 3
    float4 v; float c;
    GLD(v, c, k)
    float w = cn * c;
    sx = sx + (v.x * w); sy = sy + (v.y * w); sz = sz + (v.z * w); sw = sw + (v.w * w);
  }
#undef GLD

  // Noise norm, bit-identical: r[j] = sum over k of sq[8k+j] (sequential), tree combine.
  float4 nzv = *(const float4*)(nz_l + (size_t)node * DD + q * 4);
  float4 sq;
  sq.x = nzv.x * nzv.x; sq.y = nzv.y * nzv.y;
  sq.z = nzv.z * nzv.z; sq.w = nzv.w * nzv.w;
  float rA0 = 0.f, rA1 = 0.f, rA2 = 0.f, rA3 = 0.f;
  float rB0 = 0.f, rB1 = 0.f, rB2 = 0.f, rB3 = 0.f;
  int base = g * 16;
#pragma unroll
  for (int kk = 0; kk < 8; ++kk) {
    int le = base + 2 * kk, lo = le + 1;
    rA0 = rA0 + __shfl(sq.x, le, 64);
    rA1 = rA1 + __shfl(sq.y, le, 64);
    rA2 = rA2 + __shfl(sq.z, le, 64);
    rA3 = rA3 + __shfl(sq.w, le, 64);
    rB0 = rB0 + __shfl(sq.x, lo, 64);
    rB1 = rB1 + __shfl(sq.y, lo, 64);
    rB2 = rB2 + __shfl(sq.z, lo, 64);
    rB3 = rB3 + __shfl(sq.w, lo, 64);
  }
  float t01 = rA0 + rA1, t23 = rA2 + rA3;
  float t45 = rB0 + rB1, t67 = rB2 + rB3;
  float tot = (t01 + t23) + (t45 + t67);
  float nrm = __fsqrt_rn(tot);
  float den = fmaxf(nrm, 1e-12f);
  float4 o;
  {
    float nn = nzv.x / den;
    float sg = (sx > 0.f) ? 1.f : ((sx < 0.f) ? -1.f : 0.f);
    o.x = sx + ((sg * nn) * 0.2f);
  }
  {
    float nn = nzv.y / den;
    float sg = (sy > 0.f) ? 1.f : ((sy < 0.f) ? -1.f : 0.f);
    o.y = sy + ((sg * nn) * 0.2f);
  }
  {
    float nn = nzv.z / den;
    float sg = (sz > 0.f) ? 1.f : ((sz < 0.f) ? -1.f : 0.f);
    o.z = sz + ((sg * nn) * 0.2f);
  }
  {
    float nn = nzv.w / den;
    float sg = (sw > 0.f) ? 1.f : ((sw < 0.f) ? -1.f : 0.f);
    o.w = sw + ((sg * nn) * 0.2f);
  }
  size_t boff = (size_t)node * DD + q * 4;
  float4 a = *(const float4*)(acc + boff);
  if (LAST) {
    float4 mo;
    mo.x = (a.x + o.x) * 0.25f;
    mo.y = (a.y + o.y) * 0.25f;
    mo.z = (a.z + o.z) * 0.25f;
    mo.w = (a.w + o.w) * 0.25f;
    *(float4*)(out + boff) = mo;
  } else {
    *(float4*)(out + boff) = o;
    a.x = a.x + o.x; a.y = a.y + o.y; a.z = a.z + o.z; a.w = a.w + o.w;
    *(float4*)(acc + boff) = a;
  }
}

// Fused Rankformer layer: ONE gather pass per node. For each neighbor row v (in regs),
// recompute d = dot(e, v) via 16-lane reduce (identical bitwise on both endpoints),
// p = expf(d) (max-free softmax, exact in real arithmetic; |d| small -> no overflow),
// online-accumulate r += p*v, z += p. out = 0.5*e + 0.5*(r/max(z,1e-9)).
// Replaces score_k + zsum_k + accum_k (halves RF gather traffic, kills S/P/Zinv arrays).
__global__ __launch_bounds__(256) void rfaccum_k(const float* __restrict__ in, float* __restrict__ out,
                                                 const int* __restrict__ row, const int* __restrict__ col) {
  int wave = (blockIdx.x * blockDim.x + threadIdx.x) >> 6;
  int lane = threadIdx.x & 63;
  int g = lane >> 4, q = lane & 15;
  int node = wave * 4 + g;
  if (node >= NT) return;
  int beg = row[node], end = row[node + 1];
  size_t boff = (size_t)node * DD + q * 4;
  float4 e = *(const float4*)(in + boff);
  float rx = 0.f, ry = 0.f, rz = 0.f, rw = 0.f, zacc = 0.f;

#define VLD(dv, kk) { dv = *(const float4*)(in + (size_t)col[kk] * DD + q * 4); }
#define STEP(v)                                                              \
  {                                                                          \
    float d = fmaf(e.x, v.x, fmaf(e.y, v.y, fmaf(e.z, v.z, e.w * v.w)));     \
    d += __shfl_xor(d, 1, 64); d += __shfl_xor(d, 2, 64);                    \
    d += __shfl_xor(d, 4, 64); d += __shfl_xor(d, 8, 64);                    \
    float p = __expf(d);                                                     \
    rx = fmaf(p, v.x, rx); ry = fmaf(p, v.y, ry);                            \
    rz = fmaf(p, v.z, rz); rw = fmaf(p, v.w, rw);                            \
    zacc = zacc + p;                                                         \
  }

  float4 cv0, cv1, cv2, cv3;
  int rem = end - beg;
  int k4end = end - (rem & 3);
  int k = beg;
  if (k < k4end) {
    VLD(cv0, k) VLD(cv1, k + 1) VLD(cv2, k + 2) VLD(cv3, k + 3)
  }
  for (; k < k4end; k += 4) {
    float4 nv0, nv1, nv2, nv3;
    bool more = (k + 4) < k4end;
    if (more) {
      VLD(nv0, k + 4) VLD(nv1, k + 5) VLD(nv2, k + 6) VLD(nv3, k + 7)
    }
    STEP(cv0) STEP(cv1) STEP(cv2) STEP(cv3)
    if (more) { cv0 = nv0; cv1 = nv1; cv2 = nv2; cv3 = nv3; }
  }
  for (; k < end; ++k) {
    float4 v;
    VLD(v, k)
    STEP(v)
  }
#undef STEP
#undef VLD

  float zi = 1.f / fmaxf(zacc, 1e-9f);
  float4 o;
  o.x = 0.5f * e.x + 0.5f * (rx * zi);
  o.y = 0.5f * e.y + 0.5f * (ry * zi);
  o.z = 0.5f * e.z + 0.5f * (rz * zi);
  o.w = 0.5f * e.w + 0.5f * (rw * zi);
  *(float4*)(out + boff) = o;
}

extern "C" void kernel_launch(void* const* d_in, const int* in_sizes, int n_in,
                              void* d_out, int out_size, void* d_ws, size_t ws_size,
                              hipStream_t stream) {
  const float* user_emb = (const float*)d_in[0];
  const float* item_emb = (const float*)d_in[1];
  const float* noise    = (const float*)d_in[2];
  const int*   edge_u   = (const int*)d_in[3];
  const int*   edge_i   = (const int*)d_in[4];
  float* out = (float*)d_out;

  // ws layout (~110 MB)
  float* embA = (float*)d_ws;                      // NTD
  float* embB = embA + (size_t)NTD;                // NTD
  float* coef = embB + (size_t)NTD;                // NT+16
  int*   row  = (int*)(coef + (NT + 16));          // NT+16
  int*   cursor = row + (NT + 16);                 // NT+16
  int*   partials = cursor + (NT + 16);            // 256
  int*   eidt = partials + 256;                    // 2E
  int*   col  = eidt + 2 * (size_t)NE;             // 2E

  float* acc = out;  // layer-mean accumulator lives in d_out until the final RF pass

  const int nchunks = (NT + 1023) / 1024;

  zero_k<<<(NT + 255) / 256, 256, 0, stream>>>(cursor, NT);
  count_k<<<NCHUNK * NPART, 256, 0, stream>>>(edge_u, edge_i, cursor);
  scanA_k<<<nchunks, 1024, 0, stream>>>(cursor, row, partials, NT);
  scanB_k<<<1, 64, 0, stream>>>(partials, row, nchunks);
  scanC_k<<<nchunks, 1024, 0, stream>>>(row, cursor, coef, partials, NT);
  fill_k<<<NCHUNK * NPART, 256, 0, stream>>>(edge_u, edge_i, cursor, eidt);

  const int gwave = (NT * 64 + 255) / 256;   // 64-lane-per-node grid (sort)
  const int g4    = (NT / 4 * 64) / 256;     // 4-node-per-wave grids = 9375

  sort_k<<<gwave, 256, 0, stream>>>(row, eidt, edge_u, edge_i, col);
  init_k<<<4096, 256, 0, stream>>>(user_emb, item_emb, embA, acc);

  // L0: embA -> embB ; L1: embB -> embA ; L2(last, fused mean): embA -> embB
  gcn4_k<0><<<g4, 256, 0, stream>>>(embA, embB, acc, row, col, coef, noise + 0 * (size_t)NTD);
  gcn4_k<0><<<g4, 256, 0, stream>>>(embB, embA, acc, row, col, coef, noise + 1 * (size_t)NTD);
  gcn4_k<1><<<g4, 256, 0, stream>>>(embA, embB, acc, row, col, coef, noise + 2 * (size_t)NTD);

  // Fused RF layers: embB -> embA -> out
  rfaccum_k<<<g4, 256, 0, stream>>>(embB, embA, row, col);
  rfaccum_k<<<g4, 256, 0, stream>>>(embA, out, row, col);
}

// Round 11
// 1177.021 us; speedup vs baseline: 1.3406x; 1.0149x over previous
//
#include <hip/hip_runtime.h>
#include <math.h>

// Force numpy-style arithmetic: no FMA contraction, no reassociation.
// RF kernels use explicit fmaf() where fusion is wanted (smooth ops).
#pragma clang fp contract(off)
#pragma clang fp reassociate(off)

#define NU 100000
#define NI 50000
#define NT 150000
#define DD 64
#define NE 2000000
#define NTD (NT * DD)
#define NPART 8
#define PARTW_U (NU / NPART)   // 12500 users per partition
#define PARTW_I (NI / NPART)   // 6250 items per partition
#define NCHUNK 256
#define CHW ((NE + NCHUNK - 1) / NCHUNK)   // 7813 edges per chunk

// XCD-partitioned, endpoint-split count: user pass reads eu only.
__global__ __launch_bounds__(256) void count_u_k(const int* __restrict__ eu, int* __restrict__ cnt) {
  int part = blockIdx.x & 7;
  int chunk = blockIdx.x >> 3;
  int lo = part * PARTW_U, hi = lo + PARTW_U;
  int e0 = chunk * CHW;
  int e1 = e0 + CHW; if (e1 > NE) e1 = NE;
  for (int e = e0 + threadIdx.x; e < e1; e += 256) {
    int u = eu[e];
    if (u >= lo && u < hi) atomicAdd(&cnt[u], 1);
  }
}

__global__ __launch_bounds__(256) void count_i_k(const int* __restrict__ ei, int* __restrict__ cnt) {
  int part = blockIdx.x & 7;
  int chunk = blockIdx.x >> 3;
  int lo = part * PARTW_I, hi = lo + PARTW_I;
  int e0 = chunk * CHW;
  int e1 = e0 + CHW; if (e1 > NE) e1 = NE;
  for (int e = e0 + threadIdx.x; e < e1; e += 256) {
    int it = ei[e];
    if (it >= lo && it < hi) atomicAdd(&cnt[NU + it], 1);
  }
}

__global__ __launch_bounds__(1024) void scanA_k(const int* __restrict__ cnt, int* __restrict__ lexcl,
                                                int* __restrict__ partials, int n) {
  int idx = blockIdx.x * 1024 + threadIdx.x;
  int v = (idx < n) ? cnt[idx] : 0;
  int lane = threadIdx.x & 63;
  int wid = threadIdx.x >> 6;
  int x = v;
#pragma unroll
  for (int off = 1; off < 64; off <<= 1) {
    int y = __shfl_up(x, off, 64);
    if (lane >= off) x += y;
  }
  __shared__ int wtot[16], woff[16];
  if (lane == 63) wtot[wid] = x;
  __syncthreads();
  if (threadIdx.x == 0) {
    int a = 0;
#pragma unroll
    for (int w = 0; w < 16; ++w) { woff[w] = a; a += wtot[w]; }
    partials[blockIdx.x] = a;
  }
  __syncthreads();
  if (idx < n) lexcl[idx] = x - v + woff[wid];
}

__global__ __launch_bounds__(64) void scanB_k(int* __restrict__ partials, int* __restrict__ row, int nchunks) {
  int lane = threadIdx.x;
  int carry = 0;
  for (int base = 0; base < nchunks; base += 64) {
    int idx = base + lane;
    int v = (idx < nchunks) ? partials[idx] : 0;
    int x = v;
#pragma unroll
    for (int off = 1; off < 64; off <<= 1) {
      int y = __shfl_up(x, off, 64);
      if (lane >= off) x += y;
    }
    if (idx < nchunks) partials[idx] = carry + x - v;
    carry += __shfl(x, 63, 64);
  }
  if (lane == 0) row[NT] = carry;
}

__global__ __launch_bounds__(1024) void scanC_k(int* __restrict__ row, int* __restrict__ cursor,
                                                float* __restrict__ coef, const int* __restrict__ partials, int n) {
  int idx = blockIdx.x * 1024 + threadIdx.x;
  if (idx >= n) return;
  int c = cursor[idx];  // raw count
  int fin = row[idx] + partials[blockIdx.x];
  row[idx] = fin;
  cursor[idx] = fin;
  coef[idx] = (float)pow((double)(c > 0 ? c : 1), -0.5);
}

// XCD-partitioned, endpoint-split fill.
__global__ __launch_bounds__(256) void fill_u_k(const int* __restrict__ eu,
                                                int* __restrict__ cursor, int* __restrict__ eid) {
  int part = blockIdx.x & 7;
  int chunk = blockIdx.x >> 3;
  int lo = part * PARTW_U, hi = lo + PARTW_U;
  int e0 = chunk * CHW;
  int e1 = e0 + CHW; if (e1 > NE) e1 = NE;
  for (int e = e0 + threadIdx.x; e < e1; e += 256) {
    int u = eu[e];
    if (u >= lo && u < hi) {
      int p = atomicAdd(&cursor[u], 1);
      eid[p] = e;
    }
  }
}

__global__ __launch_bounds__(256) void fill_i_k(const int* __restrict__ ei,
                                                int* __restrict__ cursor, int* __restrict__ eid) {
  int part = blockIdx.x & 7;
  int chunk = blockIdx.x >> 3;
  int lo = part * PARTW_I, hi = lo + PARTW_I;
  int e0 = chunk * CHW;
  int e1 = e0 + CHW; if (e1 > NE) e1 = NE;
  for (int e = e0 + threadIdx.x; e < e1; e += 256) {
    int it = ei[e];
    if (it >= lo && it < hi) {
      int p = atomicAdd(&cursor[NU + it], 1);
      eid[p] = e;
    }
  }
}

// Rank-sort each segment by edge id -> col in exact edge order (deterministic).
__global__ __launch_bounds__(256) void sort_k(const int* __restrict__ row, const int* __restrict__ eid,
                                              const int* __restrict__ eu, const int* __restrict__ ei,
                                              int* __restrict__ col) {
  int wv = (blockIdx.x * blockDim.x + threadIdx.x) >> 6;
  int lane = threadIdx.x & 63;
  if (wv >= NT) return;
  int beg = row[wv], end = row[wv + 1];
  for (int idx = beg + lane; idx < end; idx += 64) {
    int my = eid[idx];
    int r = 0;
    for (int j = beg; j < end; ++j) r += (eid[j] < my);
    col[beg + r] = (wv < NU) ? (NU + ei[my]) : eu[my];
  }
}

// GCN layer: 4 nodes/wave, 16 lanes x float4 dims, depth-4+4 chunked gather pipeline.
// Arithmetic bit-identical: per-dim strict edge-order sum, separate mul/add rounding;
// noise pairwise-sum + fixed tree.
// FIRST=1: gather neighbors straight from ue/ie (uniform per-node base select; a user's
//          neighbors are all items and vice versa) and init acc = own + o (bit-identical
//          to init-then-add). LAST=1: fused layer mean (acc + o)*0.25 -> out.
template <int FIRST, int LAST>
__global__ __launch_bounds__(256) void gcn4_k(const float* __restrict__ in, float* __restrict__ out,
                                              float* __restrict__ acc,
                                              const int* __restrict__ row, const int* __restrict__ col,
                                              const float* __restrict__ coef, const float* __restrict__ nz_l,
                                              const float* __restrict__ ue, const float* __restrict__ ie) {
  int wave = (blockIdx.x * blockDim.x + threadIdx.x) >> 6;
  int lane = threadIdx.x & 63;
  int g = lane >> 4, q = lane & 15;
  int node = wave * 4 + g;
  if (node >= NT) return;
  int beg = row[node], end = row[node + 1];
  float cn = coef[node];
  float sx = 0.f, sy = 0.f, sz = 0.f, sw = 0.f;

  // Gather base: FIRST gathers from the original input tables (no init pass needed).
  const float* gbase;
  if (FIRST) {
    gbase = (node < NU) ? (ie - (size_t)NU * DD) : ue;  // user->item rows, item->user rows
  } else {
    gbase = in;
  }

#define GLD(dv, dc, kk) { int m_ = col[kk]; dc = coef[m_]; dv = *(const float4*)(gbase + (size_t)m_ * DD + q * 4); }
  float4 cv0, cv1, cv2, cv3;
  float cc0, cc1, cc2, cc3;
  int rem = end - beg;
  int k4end = end - (rem & 3);
  int k = beg;
  if (k < k4end) {
    GLD(cv0, cc0, k) GLD(cv1, cc1, k + 1) GLD(cv2, cc2, k + 2) GLD(cv3, cc3, k + 3)
  }
  for (; k < k4end; k += 4) {
    float4 nv0, nv1, nv2, nv3;
    float nc0, nc1, nc2, nc3;
    bool more = (k + 4) < k4end;
    if (more) {
      GLD(nv0, nc0, k + 4) GLD(nv1, nc1, k + 5) GLD(nv2, nc2, k + 6) GLD(nv3, nc3, k + 7)
    }
    {
      float w = cn * cc0;
      sx = sx + (cv0.x * w); sy = sy + (cv0.y * w); sz = sz + (cv0.z * w); sw = sw + (cv0.w * w);
    }
    {
      float w = cn * cc1;
      sx = sx + (cv1.x * w); sy = sy + (cv1.y * w); sz = sz + (cv1.z * w); sw = sw + (cv1.w * w);
    }
    {
      float w = cn * cc2;
      sx = sx + (cv2.x * w); sy = sy + (cv2.y * w); sz = sz + (cv2.z * w); sw = sw + (cv2.w * w);
    }
    {
      float w = cn * cc3;
      sx = sx + (cv3.x * w); sy = sy + (cv3.y * w); sz = sz + (cv3.z * w); sw = sw + (cv3.w * w);
    }
    if (more) {
      cv0 = nv0; cc0 = nc0; cv1 = nv1; cc1 = nc1;
      cv2 = nv2; cc2 = nc2; cv3 = nv3; cc3 = nc3;
    }
  }
  for (; k < end; ++k) {  // tail <= 3
    float4 v; float c;
    GLD(v, c, k)
    float w = cn * c;
    sx = sx + (v.x * w); sy = sy + (v.y * w); sz = sz + (v.z * w); sw = sw + (v.w * w);
  }
#undef GLD

  // Noise norm, bit-identical: r[j] = sum over k of sq[8k+j] (sequential), tree combine.
  float4 nzv = *(const float4*)(nz_l + (size_t)node * DD + q * 4);
  float4 sq;
  sq.x = nzv.x * nzv.x; sq.y = nzv.y * nzv.y;
  sq.z = nzv.z * nzv.z; sq.w = nzv.w * nzv.w;
  float rA0 = 0.f, rA1 = 0.f, rA2 = 0.f, rA3 = 0.f;
  float rB0 = 0.f, rB1 = 0.f, rB2 = 0.f, rB3 = 0.f;
  int base = g * 16;
#pragma unroll
  for (int kk = 0; kk < 8; ++kk) {
    int le = base + 2 * kk, lo = le + 1;
    rA0 = rA0 + __shfl(sq.x, le, 64);
    rA1 = rA1 + __shfl(sq.y, le, 64);
    rA2 = rA2 + __shfl(sq.z, le, 64);
    rA3 = rA3 + __shfl(sq.w, le, 64);
    rB0 = rB0 + __shfl(sq.x, lo, 64);
    rB1 = rB1 + __shfl(sq.y, lo, 64);
    rB2 = rB2 + __shfl(sq.z, lo, 64);
    rB3 = rB3 + __shfl(sq.w, lo, 64);
  }
  float t01 = rA0 + rA1, t23 = rA2 + rA3;
  float t45 = rB0 + rB1, t67 = rB2 + rB3;
  float tot = (t01 + t23) + (t45 + t67);
  float nrm = __fsqrt_rn(tot);
  float den = fmaxf(nrm, 1e-12f);
  float4 o;
  {
    float nn = nzv.x / den;
    float sg = (sx > 0.f) ? 1.f : ((sx < 0.f) ? -1.f : 0.f);
    o.x = sx + ((sg * nn) * 0.2f);
  }
  {
    float nn = nzv.y / den;
    float sg = (sy > 0.f) ? 1.f : ((sy < 0.f) ? -1.f : 0.f);
    o.y = sy + ((sg * nn) * 0.2f);
  }
  {
    float nn = nzv.z / den;
    float sg = (sz > 0.f) ? 1.f : ((sz < 0.f) ? -1.f : 0.f);
    o.z = sz + ((sg * nn) * 0.2f);
  }
  {
    float nn = nzv.w / den;
    float sg = (sw > 0.f) ? 1.f : ((sw < 0.f) ? -1.f : 0.f);
    o.w = sw + ((sg * nn) * 0.2f);
  }
  size_t boff = (size_t)node * DD + q * 4;
  if (FIRST) {
    // own row from input tables; acc = own + o (== init acc=own; acc+=o)
    const float* ownp = (node < NU) ? (ue + (size_t)node * DD) : (ie + (size_t)(node - NU) * DD);
    float4 own = *(const float4*)(ownp + q * 4);
    *(float4*)(out + boff) = o;
    float4 a;
    a.x = own.x + o.x; a.y = own.y + o.y; a.z = own.z + o.z; a.w = own.w + o.w;
    *(float4*)(acc + boff) = a;
  } else {
    float4 a = *(const float4*)(acc + boff);
    if (LAST) {
      float4 mo;
      mo.x = (a.x + o.x) * 0.25f;
      mo.y = (a.y + o.y) * 0.25f;
      mo.z = (a.z + o.z) * 0.25f;
      mo.w = (a.w + o.w) * 0.25f;
      *(float4*)(out + boff) = mo;
    } else {
      *(float4*)(out + boff) = o;
      a.x = a.x + o.x; a.y = a.y + o.y; a.z = a.z + o.z; a.w = a.w + o.w;
      *(float4*)(acc + boff) = a;
    }
  }
}

// Fused Rankformer layer: ONE gather pass per node (max-free softmax, r9-validated).
__global__ __launch_bounds__(256) void rfaccum_k(const float* __restrict__ in, float* __restrict__ out,
                                                 const int* __restrict__ row, const int* __restrict__ col) {
  int wave = (blockIdx.x * blockDim.x + threadIdx.x) >> 6;
  int lane = threadIdx.x & 63;
  int g = lane >> 4, q = lane & 15;
  int node = wave * 4 + g;
  if (node >= NT) return;
  int beg = row[node], end = row[node + 1];
  size_t boff = (size_t)node * DD + q * 4;
  float4 e = *(const float4*)(in + boff);
  float rx = 0.f, ry = 0.f, rz = 0.f, rw = 0.f, zacc = 0.f;

#define VLD(dv, kk) { dv = *(const float4*)(in + (size_t)col[kk] * DD + q * 4); }
#define STEP(v)                                                              \
  {                                                                          \
    float d = fmaf(e.x, v.x, fmaf(e.y, v.y, fmaf(e.z, v.z, e.w * v.w)));     \
    d += __shfl_xor(d, 1, 64); d += __shfl_xor(d, 2, 64);                    \
    d += __shfl_xor(d, 4, 64); d += __shfl_xor(d, 8, 64);                    \
    float p = __expf(d);                                                     \
    rx = fmaf(p, v.x, rx); ry = fmaf(p, v.y, ry);                            \
    rz = fmaf(p, v.z, rz); rw = fmaf(p, v.w, rw);                            \
    zacc = zacc + p;                                                         \
  }

  float4 cv0, cv1, cv2, cv3;
  int rem = end - beg;
  int k4end = end - (rem & 3);
  int k = beg;
  if (k < k4end) {
    VLD(cv0, k) VLD(cv1, k + 1) VLD(cv2, k + 2) VLD(cv3, k + 3)
  }
  for (; k < k4end; k += 4) {
    float4 nv0, nv1, nv2, nv3;
    bool more = (k + 4) < k4end;
    if (more) {
      VLD(nv0, k + 4) VLD(nv1, k + 5) VLD(nv2, k + 6) VLD(nv3, k + 7)
    }
    STEP(cv0) STEP(cv1) STEP(cv2) STEP(cv3)
    if (more) { cv0 = nv0; cv1 = nv1; cv2 = nv2; cv3 = nv3; }
  }
  for (; k < end; ++k) {
    float4 v;
    VLD(v, k)
    STEP(v)
  }
#undef STEP
#undef VLD

  float zi = 1.f / fmaxf(zacc, 1e-9f);
  float4 o;
  o.x = 0.5f * e.x + 0.5f * (rx * zi);
  o.y = 0.5f * e.y + 0.5f * (ry * zi);
  o.z = 0.5f * e.z + 0.5f * (rz * zi);
  o.w = 0.5f * e.w + 0.5f * (rw * zi);
  *(float4*)(out + boff) = o;
}

extern "C" void kernel_launch(void* const* d_in, const int* in_sizes, int n_in,
                              void* d_out, int out_size, void* d_ws, size_t ws_size,
                              hipStream_t stream) {
  const float* user_emb = (const float*)d_in[0];
  const float* item_emb = (const float*)d_in[1];
  const float* noise    = (const float*)d_in[2];
  const int*   edge_u   = (const int*)d_in[3];
  const int*   edge_i   = (const int*)d_in[4];
  float* out = (float*)d_out;

  // ws layout (~110 MB)
  float* embA = (float*)d_ws;                      // NTD
  float* embB = embA + (size_t)NTD;                // NTD
  float* coef = embB + (size_t)NTD;                // NT+16
  int*   row  = (int*)(coef + (NT + 16));          // NT+16
  int*   cursor = row + (NT + 16);                 // NT+16
  int*   partials = cursor + (NT + 16);            // 256
  int*   eidt = partials + 256;                    // 2E
  int*   col  = eidt + 2 * (size_t)NE;             // 2E

  float* acc = out;  // layer-mean accumulator lives in d_out until the final RF pass

  const int nchunks = (NT + 1023) / 1024;

  hipMemsetAsync(cursor, 0, (size_t)NT * sizeof(int), stream);
  count_u_k<<<NCHUNK * NPART, 256, 0, stream>>>(edge_u, cursor);
  count_i_k<<<NCHUNK * NPART, 256, 0, stream>>>(edge_i, cursor);
  scanA_k<<<nchunks, 1024, 0, stream>>>(cursor, row, partials, NT);
  scanB_k<<<1, 64, 0, stream>>>(partials, row, nchunks);
  scanC_k<<<nchunks, 1024, 0, stream>>>(row, cursor, coef, partials, NT);
  fill_u_k<<<NCHUNK * NPART, 256, 0, stream>>>(edge_u, cursor, eidt);
  fill_i_k<<<NCHUNK * NPART, 256, 0, stream>>>(edge_i, cursor, eidt);

  const int gwave = (NT * 64 + 255) / 256;   // 64-lane-per-node grid (sort)
  const int g4    = (NT / 4 * 64) / 256;     // 4-node-per-wave grids = 9375

  sort_k<<<gwave, 256, 0, stream>>>(row, eidt, edge_u, edge_i, col);

  // L0 (FIRST, gathers from ue/ie, inits acc): -> embB
  gcn4_k<1, 0><<<g4, 256, 0, stream>>>(nullptr, embB, acc, row, col, coef,
                                       noise + 0 * (size_t)NTD, user_emb, item_emb);
  // L1: embB -> embA
  gcn4_k<0, 0><<<g4, 256, 0, stream>>>(embB, embA, acc, row, col, coef,
                                       noise + 1 * (size_t)NTD, user_emb, item_emb);
  // L2 (LAST, fused mean): embA -> embB
  gcn4_k<0, 1><<<g4, 256, 0, stream>>>(embA, embB, acc, row, col, coef,
                                       noise + 2 * (size_t)NTD, user_emb, item_emb);

  // Fused RF layers: embB -> embA -> out
  rfaccum_k<<<g4, 256, 0, stream>>>(embB, embA, row, col);
  rfaccum_k<<<g4, 256, 0, stream>>>(embA, out, row, col);
}